// Round 2
// baseline (146.882 us; speedup 1.0000x reference)
//
#include <hip/hip_runtime.h>
#include <cstdint>

#define IMG_H 512
#define IMG_W 512
#define ROW_BYTES (IMG_W * 4)
#define NPLANES 48                  // 16 batch * 3 channels
#define PLANE_SZ (IMG_H * IMG_W)
#define N_ELEM (NPLANES * PLANE_SZ) // 12,582,912

#define TILE_W 48
#define TILE_H 16
#define GX 11
#define GY 32
#define NBLOCKS (GX * GY * NPLANES) // 16896
#define VPITCH 59                   // stored halo cols 0..57 (+1 pad)

#define SSIM_C1 1e-4f
#define SSIM_C2 9e-4f

typedef float f32x2 __attribute__((ext_vector_type(2)));

// Raw buffer load: OOB (row<0 / row>=H via soffset; bad col via huge voffset)
// returns 0.0f in hardware = free 'SAME' zero padding, zero bounds VALU.
typedef int rsrc_t __attribute__((ext_vector_type(4)));
__device__ float
llvm_amdgcn_raw_buffer_load_fp32(rsrc_t srsrc, int voffset, int soffset,
                                 int glc_slc) __asm("llvm.amdgcn.raw.buffer.load.f32");

__device__ inline rsrc_t make_rsrc(const void* p, int bytes) {
    rsrc_t r;
    r.x = (int)(uint32_t)(uintptr_t)p;       // base lo
    r.y = (int)((uintptr_t)p >> 32);         // base hi, stride=0
    r.z = bytes;                             // num_records (bytes)
    r.w = 0x00020000;                        // raw dword SRD word3
    return r;
}

// Separable 11x11 Gaussian over 4 channels (s=x+y, d=x-y, s^2, d^2),
// SSIM map, per-block partial.
// R6 theory: R5 fixed occupancy (42->70%) but time was neutral -> VALU-issue
// bound (52.5us * 71% busy ~= 37us of issue). The channel pairs (s,d)/(s2,d2)
// share weights, so express accumulation on f32x2 -> v_pk_fma_f32 (gfx950
// full-rate packed fp32) halves FMA issue slots: ~128 -> ~75 VALU ops/px.
__global__ __launch_bounds__(256, 8) void ssim_tile_kernel(
    const float* __restrict__ img1, const float* __restrict__ img2,
    double* __restrict__ partials)
{
#pragma clang fp contract(fast)
    __shared__ float4 vs[TILE_H][VPITCH]; // 15.1 KB -> 8 blocks/CU
    __shared__ double wred[4];

    // exact gaussian(ws=11, sigma=1.5) weights (normalized, ~1e-8 abs)
    const float gw[11] = {0.00102838f, 0.00759876f, 0.03600077f, 0.10936069f,
                          0.21300553f, 0.26601172f, 0.21300553f, 0.10936069f,
                          0.03600077f, 0.00759876f, 0.00102838f};

    const int tid  = threadIdx.x;
    const int lane = tid & 63;
    const int wv   = tid >> 6;
    const int ox = blockIdx.x * TILE_W;
    const int oy = blockIdx.y * TILE_H;

    const float* p1 = img1 + (size_t)blockIdx.z * PLANE_SZ;
    const float* p2 = img2 + (size_t)blockIdx.z * PLANE_SZ;
    const rsrc_t rr1 = make_rsrc(p1, PLANE_SZ * 4);
    const rsrc_t rr2 = make_rsrc(p2, PLANE_SZ * 4);

    // ---- vertical pass: wave wv -> output rows [oy+wv*4, +4), lane = halo col
    {
        const int r0 = wv * 4;
        const int srow0 = __builtin_amdgcn_readfirstlane(oy + r0 - 5); // SGPR
        const int gcol = ox + lane - 5;
        // lanes >= 58 are never consumed by the horizontal pass: mask their
        // (otherwise in-bounds) loads too -> ~9% less vertical fetch traffic.
        const int coff = (lane < 58 && (unsigned)gcol < (unsigned)IMG_W)
                             ? (gcol * 4) : 0x48000000;

        // Stage 1: issue ALL 28 loads back-to-back (max memory-level parallelism)
        float xs[14], ys[14];
        #pragma unroll
        for (int i = 0; i < 14; ++i) {
            const int soff = (srow0 + i) * ROW_BYTES;  // SGPR soffset
            xs[i] = llvm_amdgcn_raw_buffer_load_fp32(rr1, coff, soff, 0);
            ys[i] = llvm_amdgcn_raw_buffer_load_fp32(rr2, coff, soff, 0);
        }

        // Stage 2: consume (packed fp32: one v_pk_fma_f32 per channel-pair)
        f32x2 accA[4], accB[4];
        #pragma unroll
        for (int o = 0; o < 4; ++o) { accA[o] = (f32x2)0.f; accB[o] = (f32x2)0.f; }
        #pragma unroll
        for (int i = 0; i < 14; ++i) {
            const float s = xs[i] + ys[i], d = xs[i] - ys[i];
            f32x2 sd; sd.x = s; sd.y = d;
            const f32x2 sq = sd * sd;               // v_pk_mul_f32
            #pragma unroll
            for (int o = 0; o < 4; ++o) {
                const int k = i - o;              // tap index (static)
                if (k >= 0 && k <= 10) {
                    f32x2 w2; w2.x = gw[k]; w2.y = gw[k];
                    accA[o] += w2 * sd;             // -> v_pk_fma_f32
                    accB[o] += w2 * sq;             // -> v_pk_fma_f32
                }
            }
        }
        if (lane < 58) {                          // only cols used by horizontal
            #pragma unroll
            for (int o = 0; o < 4; ++o)
                vs[r0 + o][lane] = make_float4(accA[o].x, accA[o].y,
                                               accB[o].x, accB[o].y);
        }
    }
    __syncthreads();

    // ---- horizontal pass + SSIM: thread -> 1 row x 3 consecutive cols
    float lsum = 0.f;
    {
        const int r  = tid >> 4;                 // 16 rows
        const int c0 = (tid & 15) * 3;           // max read col 45+12=57 < 58
        f32x2 mA[3], mB[3];
        #pragma unroll
        for (int j = 0; j < 3; ++j) { mA[j] = (f32x2)0.f; mB[j] = (f32x2)0.f; }
        #pragma unroll
        for (int t = 0; t < 13; ++t) {
            const float4 v = vs[r][c0 + t];
            f32x2 vA; vA.x = v.x; vA.y = v.y;
            f32x2 vB; vB.x = v.z; vB.y = v.w;
            #pragma unroll
            for (int j = 0; j < 3; ++j) {
                const int k = t - j;
                if (k >= 0 && k <= 10) {
                    f32x2 w2; w2.x = gw[k]; w2.y = gw[k];
                    mA[j] += w2 * vA;               // -> v_pk_fma_f32
                    mB[j] += w2 * vB;               // -> v_pk_fma_f32
                }
            }
        }
        #pragma unroll
        for (int j = 0; j < 3; ++j) {
            if (ox + c0 + j < IMG_W) {           // clip right-edge partial tile
                const float mus = mA[j].x, mud = mA[j].y;
                const float es2 = mB[j].x, ed2 = mB[j].y;
                const float a = mus * mus, b = mud * mud;
                // mu1 = (mus+mud)/2, mu2 = (mus-mud)/2:
                const float num1 = (a - b) * 0.5f + SSIM_C1;               // 2*mu1*mu2 + C1
                const float den1 = (a + b) * 0.5f + SSIM_C1;               // mu1^2+mu2^2 + C1
                const float num2 = (es2 - ed2 - (a - b)) * 0.5f + SSIM_C2; // 2*sigma12 + C2
                const float den2 = (es2 + ed2 - (a + b)) * 0.5f + SSIM_C2; // s1+s2 + C2
                lsum += (num1 * num2) * __builtin_amdgcn_rcpf(den1 * den2);
            }
        }
    }

    // ---- block reduction -> one partial per block, plain store (no atomics)
    #pragma unroll
    for (int off = 32; off > 0; off >>= 1)
        lsum += __shfl_down(lsum, off, 64);
    if (lane == 0) wred[wv] = (double)lsum;
    __syncthreads();
    if (tid == 0) {
        const int bid = blockIdx.x + GX * (blockIdx.y + GY * blockIdx.z);
        partials[bid] = wred[0] + wred[1] + wred[2] + wred[3];
    }
}

// 1 block x 1024 threads: ~17 independent loads per thread, then tree-reduce.
__global__ __launch_bounds__(1024) void ssim_finalize_kernel(
    const double* __restrict__ partials, float* __restrict__ out)
{
    __shared__ double wred[16];
    const int tid  = threadIdx.x;
    const int lane = tid & 63;
    const int wv   = tid >> 6;
    double s = 0.0;
    #pragma unroll
    for (int i = 0; i < 17; ++i) {
        const int idx = tid + i * 1024;
        if (idx < NBLOCKS) s += partials[idx];
    }
    #pragma unroll
    for (int off = 32; off > 0; off >>= 1)
        s += __shfl_down(s, off, 64);
    if (lane == 0) wred[wv] = s;
    __syncthreads();
    if (wv == 0) {
        double v = (lane < 16) ? wred[lane] : 0.0;
        v += __shfl_down(v, 8, 64);
        v += __shfl_down(v, 4, 64);
        v += __shfl_down(v, 2, 64);
        v += __shfl_down(v, 1, 64);
        if (lane == 0) out[0] = (float)(v / (double)N_ELEM);
    }
}

extern "C" void kernel_launch(void* const* d_in, const int* in_sizes, int n_in,
                              void* d_out, int out_size, void* d_ws, size_t ws_size,
                              hipStream_t stream)
{
    const float* img1 = (const float*)d_in[0];
    const float* img2 = (const float*)d_in[1];
    double* partials  = (double*)d_ws;          // 16896 * 8B = 135 KB scratch
    float* out        = (float*)d_out;

    dim3 grid(GX, GY, NPLANES);
    ssim_tile_kernel<<<grid, dim3(256), 0, stream>>>(img1, img2, partials);
    ssim_finalize_kernel<<<1, dim3(1024), 0, stream>>>(partials, out);
}

// Round 3
// 143.412 us; speedup vs baseline: 1.0242x; 1.0242x over previous
//
#include <hip/hip_runtime.h>
#include <cstdint>

#define IMG_H 512
#define IMG_W 512
#define ROW_BYTES (IMG_W * 4)
#define NPLANES 48                  // 16 batch * 3 channels
#define PLANE_SZ (IMG_H * IMG_W)
#define N_ELEM (NPLANES * PLANE_SZ) // 12,582,912

#define TILE_W 48
#define TILE_H 16
#define GX 11
#define GY 32
#define NBLOCKS (GX * GY * NPLANES) // 16896
#define VPITCH 59                   // stored halo cols 0..57 (+1 pad)

#define SSIM_C1 1e-4f
#define SSIM_C2 9e-4f

typedef float f32x2 __attribute__((ext_vector_type(2)));

// Raw buffer load: OOB (row<0 / row>=H via soffset; bad col via huge voffset)
// returns 0.0f in hardware = free 'SAME' zero padding, zero bounds VALU.
typedef int rsrc_t __attribute__((ext_vector_type(4)));
__device__ float
llvm_amdgcn_raw_buffer_load_fp32(rsrc_t srsrc, int voffset, int soffset,
                                 int glc_slc) __asm("llvm.amdgcn.raw.buffer.load.f32");

__device__ inline rsrc_t make_rsrc(const void* p, int bytes) {
    rsrc_t r;
    r.x = (int)(uint32_t)(uintptr_t)p;       // base lo
    r.y = (int)((uintptr_t)p >> 32);         // base hi, stride=0
    r.z = bytes;                             // num_records (bytes)
    r.w = 0x00020000;                        // raw dword SRD word3
    return r;
}

// explicit packed fma: llvm.fma.v2f32 -> V_PK_FMA_F32 on gfx950
__device__ inline f32x2 pk_fma(f32x2 a, f32x2 b, f32x2 c) {
    return __builtin_elementwise_fma(a, b, c);
}

// Separable 11x11 Gaussian over 4 channels (s=x+y, d=x-y, s^2, d^2),
// SSIM map, per-block partial.
// R7: R6 (f32x2 @ launch_bounds(256,8)) regressed because VGPR cap 32 starved
// the allocator: 28-load batch got chunked (vmcnt serialization) AND f32x2
// pairs need even alignment. Fix: (256,6) -> 85 VGPR cap (28 dests + 16 acc +
// addr ~= 60 fits), and __builtin_elementwise_fma -> guaranteed V_PK_FMA_F32
// instead of hoping fp-contract fuses vector mul+add.
__global__ __launch_bounds__(256, 6) void ssim_tile_kernel(
    const float* __restrict__ img1, const float* __restrict__ img2,
    double* __restrict__ partials)
{
    __shared__ float4 vs[TILE_H][VPITCH]; // 15.1 KB
    __shared__ double wred[4];

    // exact gaussian(ws=11, sigma=1.5) weights (normalized, ~1e-8 abs)
    const float gw[11] = {0.00102838f, 0.00759876f, 0.03600077f, 0.10936069f,
                          0.21300553f, 0.26601172f, 0.21300553f, 0.10936069f,
                          0.03600077f, 0.00759876f, 0.00102838f};

    const int tid  = threadIdx.x;
    const int lane = tid & 63;
    const int wv   = tid >> 6;
    const int ox = blockIdx.x * TILE_W;
    const int oy = blockIdx.y * TILE_H;

    const float* p1 = img1 + (size_t)blockIdx.z * PLANE_SZ;
    const float* p2 = img2 + (size_t)blockIdx.z * PLANE_SZ;
    const rsrc_t rr1 = make_rsrc(p1, PLANE_SZ * 4);
    const rsrc_t rr2 = make_rsrc(p2, PLANE_SZ * 4);

    // ---- vertical pass: wave wv -> output rows [oy+wv*4, +4), lane = halo col
    {
        const int r0 = wv * 4;
        const int srow0 = __builtin_amdgcn_readfirstlane(oy + r0 - 5); // SGPR
        const int gcol = ox + lane - 5;
        // lanes >= 58 are never consumed by the horizontal pass: mask their
        // (otherwise in-bounds) loads too -> ~9% less vertical fetch traffic.
        const int coff = (lane < 58 && (unsigned)gcol < (unsigned)IMG_W)
                             ? (gcol * 4) : 0x48000000;

        // Stage 1: issue ALL 28 loads back-to-back (max memory-level parallelism)
        float xs[14], ys[14];
        #pragma unroll
        for (int i = 0; i < 14; ++i) {
            const int soff = (srow0 + i) * ROW_BYTES;  // SGPR soffset
            xs[i] = llvm_amdgcn_raw_buffer_load_fp32(rr1, coff, soff, 0);
            ys[i] = llvm_amdgcn_raw_buffer_load_fp32(rr2, coff, soff, 0);
        }

        // Stage 2: consume (packed fp32: one v_pk_fma_f32 per channel-pair)
        f32x2 accA[4], accB[4];
        #pragma unroll
        for (int o = 0; o < 4; ++o) { accA[o] = (f32x2)0.f; accB[o] = (f32x2)0.f; }
        #pragma unroll
        for (int i = 0; i < 14; ++i) {
            const float s = xs[i] + ys[i], d = xs[i] - ys[i];
            f32x2 sd; sd.x = s; sd.y = d;
            const f32x2 sq = sd * sd;               // v_pk_mul_f32
            #pragma unroll
            for (int o = 0; o < 4; ++o) {
                const int k = i - o;              // tap index (static)
                if (k >= 0 && k <= 10) {
                    f32x2 w2; w2.x = gw[k]; w2.y = gw[k];
                    accA[o] = pk_fma(w2, sd, accA[o]);   // v_pk_fma_f32
                    accB[o] = pk_fma(w2, sq, accB[o]);   // v_pk_fma_f32
                }
            }
        }
        if (lane < 58) {                          // only cols used by horizontal
            #pragma unroll
            for (int o = 0; o < 4; ++o)
                vs[r0 + o][lane] = make_float4(accA[o].x, accA[o].y,
                                               accB[o].x, accB[o].y);
        }
    }
    __syncthreads();

    // ---- horizontal pass + SSIM: thread -> 1 row x 3 consecutive cols
    float lsum = 0.f;
    {
        const int r  = tid >> 4;                 // 16 rows
        const int c0 = (tid & 15) * 3;           // max read col 45+12=57 < 58
        f32x2 mA[3], mB[3];
        #pragma unroll
        for (int j = 0; j < 3; ++j) { mA[j] = (f32x2)0.f; mB[j] = (f32x2)0.f; }
        #pragma unroll
        for (int t = 0; t < 13; ++t) {
            const float4 v = vs[r][c0 + t];
            f32x2 vA; vA.x = v.x; vA.y = v.y;
            f32x2 vB; vB.x = v.z; vB.y = v.w;
            #pragma unroll
            for (int j = 0; j < 3; ++j) {
                const int k = t - j;
                if (k >= 0 && k <= 10) {
                    f32x2 w2; w2.x = gw[k]; w2.y = gw[k];
                    mA[j] = pk_fma(w2, vA, mA[j]);       // v_pk_fma_f32
                    mB[j] = pk_fma(w2, vB, mB[j]);       // v_pk_fma_f32
                }
            }
        }
        #pragma unroll
        for (int j = 0; j < 3; ++j) {
            if (ox + c0 + j < IMG_W) {           // clip right-edge partial tile
                const float mus = mA[j].x, mud = mA[j].y;
                const float es2 = mB[j].x, ed2 = mB[j].y;
                const float a = mus * mus, b = mud * mud;
                // mu1 = (mus+mud)/2, mu2 = (mus-mud)/2:
                const float num1 = (a - b) * 0.5f + SSIM_C1;               // 2*mu1*mu2 + C1
                const float den1 = (a + b) * 0.5f + SSIM_C1;               // mu1^2+mu2^2 + C1
                const float num2 = (es2 - ed2 - (a - b)) * 0.5f + SSIM_C2; // 2*sigma12 + C2
                const float den2 = (es2 + ed2 - (a + b)) * 0.5f + SSIM_C2; // s1+s2 + C2
                lsum += (num1 * num2) * __builtin_amdgcn_rcpf(den1 * den2);
            }
        }
    }

    // ---- block reduction -> one partial per block, plain store (no atomics)
    #pragma unroll
    for (int off = 32; off > 0; off >>= 1)
        lsum += __shfl_down(lsum, off, 64);
    if (lane == 0) wred[wv] = (double)lsum;
    __syncthreads();
    if (tid == 0) {
        const int bid = blockIdx.x + GX * (blockIdx.y + GY * blockIdx.z);
        partials[bid] = wred[0] + wred[1] + wred[2] + wred[3];
    }
}

// 1 block x 1024 threads: ~17 independent loads per thread, then tree-reduce.
__global__ __launch_bounds__(1024) void ssim_finalize_kernel(
    const double* __restrict__ partials, float* __restrict__ out)
{
    __shared__ double wred[16];
    const int tid  = threadIdx.x;
    const int lane = tid & 63;
    const int wv   = tid >> 6;
    double s = 0.0;
    #pragma unroll
    for (int i = 0; i < 17; ++i) {
        const int idx = tid + i * 1024;
        if (idx < NBLOCKS) s += partials[idx];
    }
    #pragma unroll
    for (int off = 32; off > 0; off >>= 1)
        s += __shfl_down(s, off, 64);
    if (lane == 0) wred[wv] = s;
    __syncthreads();
    if (wv == 0) {
        double v = (lane < 16) ? wred[lane] : 0.0;
        v += __shfl_down(v, 8, 64);
        v += __shfl_down(v, 4, 64);
        v += __shfl_down(v, 2, 64);
        v += __shfl_down(v, 1, 64);
        if (lane == 0) out[0] = (float)(v / (double)N_ELEM);
    }
}

extern "C" void kernel_launch(void* const* d_in, const int* in_sizes, int n_in,
                              void* d_out, int out_size, void* d_ws, size_t ws_size,
                              hipStream_t stream)
{
    const float* img1 = (const float*)d_in[0];
    const float* img2 = (const float*)d_in[1];
    double* partials  = (double*)d_ws;          // 16896 * 8B = 135 KB scratch
    float* out        = (float*)d_out;

    dim3 grid(GX, GY, NPLANES);
    ssim_tile_kernel<<<grid, dim3(256), 0, stream>>>(img1, img2, partials);
    ssim_finalize_kernel<<<1, dim3(1024), 0, stream>>>(partials, out);
}